// Round 1
// baseline (417.176 us; speedup 1.0000x reference)
//
#include <hip/hip_runtime.h>

// Problem constants (fixed by reference: B=4, C=512, H=W=64, MID=64)
#define BB 4
#define CD 512
#define NP 4096
#define MID 64

typedef _Float16 half8 __attribute__((ext_vector_type(8)));
typedef _Float16 half4 __attribute__((ext_vector_type(4)));
typedef float floatx4 __attribute__((ext_vector_type(4)));

#define LOG2E 1.4426950408889634f

// ---------------------------------------------------------------------------
// Kernel 1: pack wq|wk|wv -> fp16 [640][512], concat biases (fp32 [640]).
// log2(e) folded into wq/bq so softmax can use exp2 (raw v_exp_f32).
// ---------------------------------------------------------------------------
__global__ __launch_bounds__(256) void prep_w(
    const float* __restrict__ wq, const float* __restrict__ wk,
    const float* __restrict__ wv, const float* __restrict__ bq,
    const float* __restrict__ bk, const float* __restrict__ bv,
    _Float16* __restrict__ w_h, float* __restrict__ bias) {
  int idx = blockIdx.x * 256 + threadIdx.x;
  for (int i = idx; i < 640 * 512; i += gridDim.x * 256) {
    int r = i >> 9, c = i & 511;
    float v = (r < 64) ? wq[(r << 9) + c] * LOG2E
            : (r < 128) ? wk[((r - 64) << 9) + c]
                        : wv[((r - 128) << 9) + c];
    w_h[i] = (_Float16)v;
  }
  if (idx < 640) {
    float v = (idx < 64) ? bq[idx] * LOG2E
            : (idx < 128) ? bk[idx - 64]
                          : bv[idx - 128];
    bias[idx] = v;
  }
}

// ---------------------------------------------------------------------------
// Kernel 2: transpose x [b][c][n] fp32 -> xt [b][n][c] fp16 (64x64 LDS tiles)
// ---------------------------------------------------------------------------
__global__ __launch_bounds__(256) void transpose_x(const float* __restrict__ x,
                                                   _Float16* __restrict__ xt) {
  __shared__ float tile[64][65];
  int b = blockIdx.z, c0 = blockIdx.y * 64, n0 = blockIdx.x * 64;
  int t = threadIdx.x;
  const float* xb = x + (size_t)b * CD * NP;
  for (int k = 0; k < 16; k++) {
    int cl = k * 4 + (t >> 6);
    int nl = t & 63;
    tile[cl][nl] = xb[(size_t)(c0 + cl) * NP + n0 + nl];
  }
  __syncthreads();
  _Float16* xtb = xt + ((size_t)b * NP + n0) * CD + c0;
  for (int k = 0; k < 16; k++) {
    int nl = k * 4 + (t >> 6);
    int cl = t & 63;
    xtb[(size_t)nl * CD + cl] = (_Float16)tile[cl][nl];
  }
}

// ---------------------------------------------------------------------------
// Kernel 3: fused QKV projection. One wave per block, 64 rows x 64 cols tile.
// D[row=w_row][col=n] = sum_c W[row][c] * xt[n][c]  (A=W, B=xt)
// q,k stored [b][n][64] fp16 (m contiguous); v stored [b][d][n] fp16.
// ---------------------------------------------------------------------------
__global__ __launch_bounds__(64) void proj_qkv(
    const _Float16* __restrict__ w_h, const float* __restrict__ bias,
    const _Float16* __restrict__ xt, _Float16* __restrict__ q_h,
    _Float16* __restrict__ k_h, _Float16* __restrict__ v_h) {
  int lane = threadIdx.x;
  int col = lane & 15, quad = lane >> 4;
  int rb = blockIdx.x;          // 0..9  (64 W-rows each)
  int nb = blockIdx.y;          // 0..63 (64 positions each)
  int b = blockIdx.z;
  int r0 = rb * 64, n0 = nb * 64;
  const _Float16* xtb = xt + ((size_t)b * NP + n0) * CD;

  floatx4 acc[4][4] = {};
  for (int c = 0; c < CD; c += 32) {
    half8 a[4], bf[4];
#pragma unroll
    for (int i = 0; i < 4; i++)
      a[i] = *(const half8*)(w_h + (size_t)(r0 + i * 16 + col) * CD + c + quad * 8);
#pragma unroll
    for (int j = 0; j < 4; j++)
      bf[j] = *(const half8*)(xtb + (size_t)(j * 16 + col) * CD + c + quad * 8);
#pragma unroll
    for (int i = 0; i < 4; i++)
#pragma unroll
      for (int j = 0; j < 4; j++)
        acc[i][j] = __builtin_amdgcn_mfma_f32_16x16x32_f16(a[i], bf[j], acc[i][j], 0, 0, 0);
  }

#pragma unroll
  for (int i = 0; i < 4; i++) {
    float bi[4];
#pragma unroll
    for (int rr = 0; rr < 4; rr++) bi[rr] = bias[r0 + i * 16 + quad * 4 + rr];
    if (rb < 2) {
      // q or k: store [n][m], 4 contiguous m per lane -> 8B packed store
      _Float16* dst = (rb == 0 ? q_h : k_h) + (size_t)b * NP * MID;
#pragma unroll
      for (int j = 0; j < 4; j++) {
        int n = n0 + j * 16 + col;
        half4 pk;
#pragma unroll
        for (int rr = 0; rr < 4; rr++) pk[rr] = (_Float16)(acc[i][j][rr] + bi[rr]);
        *(half4*)(dst + (size_t)n * MID + i * 16 + quad * 4) = pk;
      }
    } else {
      int dbase = (rb - 2) * 64 + i * 16 + quad * 4;
#pragma unroll
      for (int j = 0; j < 4; j++) {
        int n = n0 + j * 16 + col;
#pragma unroll
        for (int rr = 0; rr < 4; rr++)
          v_h[((size_t)b * CD + dbase + rr) * NP + n] = (_Float16)(acc[i][j][rr] + bi[rr]);
      }
    }
  }
}

// ---------------------------------------------------------------------------
// Kernel 4: row max of S = q k^T (log2-domain logits). 4 waves x 16 queries.
// ---------------------------------------------------------------------------
__global__ __launch_bounds__(256) void rowmax(const _Float16* __restrict__ q_h,
                                              const _Float16* __restrict__ k_h,
                                              float* __restrict__ M) {
  int qb = blockIdx.x, b = blockIdx.y;
  int t = threadIdx.x, w = t >> 6, lane = t & 63;
  int col = lane & 15, quad = lane >> 4;
  int q0 = qb * 64 + w * 16;
  const _Float16* qp = q_h + ((size_t)b * NP + q0) * MID;
  half8 aq0 = *(const half8*)(qp + (size_t)col * MID + quad * 8);
  half8 aq1 = *(const half8*)(qp + (size_t)col * MID + 32 + quad * 8);
  const _Float16* kp = k_h + (size_t)b * NP * MID;
  float m[4] = {-1e30f, -1e30f, -1e30f, -1e30f};
  for (int n = 0; n < NP; n += 16) {
    half8 bk0 = *(const half8*)(kp + (size_t)(n + col) * MID + quad * 8);
    half8 bk1 = *(const half8*)(kp + (size_t)(n + col) * MID + 32 + quad * 8);
    floatx4 s = {};
    s = __builtin_amdgcn_mfma_f32_16x16x32_f16(aq0, bk0, s, 0, 0, 0);
    s = __builtin_amdgcn_mfma_f32_16x16x32_f16(aq1, bk1, s, 0, 0, 0);
#pragma unroll
    for (int r = 0; r < 4; r++) m[r] = fmaxf(m[r], s[r]);
  }
#pragma unroll
  for (int r = 0; r < 4; r++)
    for (int off = 1; off < 16; off <<= 1)
      m[r] = fmaxf(m[r], __shfl_xor(m[r], off));
  if (col == 0) {
#pragma unroll
    for (int r = 0; r < 4; r++)
      M[(size_t)b * NP + q0 + quad * 4 + r] = m[r];
  }
}

// ---------------------------------------------------------------------------
// Kernel 5: attention + PV + epilogue.
// Block = 4 waves, covers 64 queries x 128 d-slice. Loop over 64-key chunks:
//   stage K[64x64], V[128x64] tiles in LDS -> scores (wave-private 16q) ->
//   P=exp2(s-M) -> LDS pbuf -> PV as O^T (A=V, B=P) -> coalesced epilogue.
// 1-D grid of 1024 with XCD swizzle: one batch's V (4MB) per XCD-pair L2.
// ---------------------------------------------------------------------------
__global__ __launch_bounds__(256, 4) void attn_pv(
    const _Float16* __restrict__ q_h, const _Float16* __restrict__ k_h,
    const _Float16* __restrict__ v_h, const float* __restrict__ M,
    const float* __restrict__ x, const float* __restrict__ alpha_p,
    float* __restrict__ out) {
  // XCD-aware swizzle (perf heuristic only; bijective over 1024 blocks)
  int bid = blockIdx.x;
  int xcd = bid & 7;
  int slot = bid >> 3;                 // 0..127
  int b = xcd >> 1;                    // 0..3
  int local = (xcd & 1) + 2 * slot;    // 0..255
  int qb = local & 63;                 // 0..63
  int ds = local >> 6;                 // 0..3

  int t = threadIdx.x, w = t >> 6, lane = t & 63;
  int col = lane & 15, quad = lane >> 4;
  int q0 = qb * 64 + w * 16;
  int d0 = ds * 128;

  __shared__ _Float16 vtile[128 * 72];
  __shared__ _Float16 ktile[64 * 72];
  __shared__ _Float16 pbuf[4][16 * 72];
  __shared__ float lbuf[4][16];

  const _Float16* qp = q_h + ((size_t)b * NP + q0) * MID;
  half8 aq0 = *(const half8*)(qp + (size_t)col * MID + quad * 8);
  half8 aq1 = *(const half8*)(qp + (size_t)col * MID + 32 + quad * 8);
  float Mr[4];
#pragma unroll
  for (int r = 0; r < 4; r++) Mr[r] = M[(size_t)b * NP + q0 + quad * 4 + r];

  const _Float16* kp = k_h + (size_t)b * NP * MID;
  const _Float16* vp = v_h + ((size_t)b * CD + d0) * NP;

  floatx4 acc[8] = {};
  float lp[4] = {0.f, 0.f, 0.f, 0.f};

  for (int nc = 0; nc < NP; nc += 64) {
    __syncthreads();
    // stage V[128 d][64 n] and K[64 n][64 m] into LDS (16B units)
#pragma unroll
    for (int k = 0; k < 4; k++) {
      int u = t + k * 256;
      int dd = u >> 3, off = (u & 7) * 8;
      *(half8*)(vtile + dd * 72 + off) =
          *(const half8*)(vp + (size_t)dd * NP + nc + off);
    }
#pragma unroll
    for (int k = 0; k < 2; k++) {
      int u = t + k * 256;
      int nn = u >> 3, off = (u & 7) * 8;
      *(half8*)(ktile + nn * 72 + off) =
          *(const half8*)(kp + (size_t)(nc + nn) * MID + off);
    }
    __syncthreads();

    // scores for this wave's 16 queries vs 64 keys; P -> pbuf (wave-private)
#pragma unroll
    for (int kt = 0; kt < 4; kt++) {
      half8 bk0 = *(const half8*)(ktile + (kt * 16 + col) * 72 + quad * 8);
      half8 bk1 = *(const half8*)(ktile + (kt * 16 + col) * 72 + 32 + quad * 8);
      floatx4 s = {};
      s = __builtin_amdgcn_mfma_f32_16x16x32_f16(aq0, bk0, s, 0, 0, 0);
      s = __builtin_amdgcn_mfma_f32_16x16x32_f16(aq1, bk1, s, 0, 0, 0);
#pragma unroll
      for (int r = 0; r < 4; r++) {
        float p = exp2f(s[r] - Mr[r]);   // logits already in log2 domain
        lp[r] += p;
        pbuf[w][(quad * 4 + r) * 72 + kt * 16 + col] = (_Float16)p;
      }
    }

    // PV as O^T: D[row=d][col=q] += V[d][n] * P^T[n][q]
#pragma unroll
    for (int f = 0; f < 2; f++) {
      half8 bp = *(const half8*)(&pbuf[w][col * 72 + f * 32 + quad * 8]);
#pragma unroll
      for (int dt = 0; dt < 8; dt++) {
        half8 av = *(const half8*)(vtile + (dt * 16 + col) * 72 + f * 32 + quad * 8);
        acc[dt] = __builtin_amdgcn_mfma_f32_16x16x32_f16(av, bp, acc[dt], 0, 0, 0);
      }
    }
  }

  // reduce l across the 16 lanes of each quad, redistribute by q-local
#pragma unroll
  for (int r = 0; r < 4; r++)
    for (int off = 1; off < 16; off <<= 1)
      lp[r] += __shfl_xor(lp[r], off);
  if (col == 0) {
#pragma unroll
    for (int r = 0; r < 4; r++) lbuf[w][quad * 4 + r] = lp[r];
  }
  __syncthreads();
  float linv = 1.0f / lbuf[w][col];
  float alpha = alpha_p[0];

  const float* xp = x + ((size_t)b * CD + d0) * NP;
  float* op = out + ((size_t)b * CD + d0) * NP;
#pragma unroll
  for (int dt = 0; dt < 8; dt++) {
#pragma unroll
    for (int r = 0; r < 4; r++) {
      size_t idx = (size_t)(dt * 16 + quad * 4 + r) * NP + q0 + col;
      op[idx] = alpha * acc[dt][r] * linv + xp[idx];
    }
  }
}

// ---------------------------------------------------------------------------
extern "C" void kernel_launch(void* const* d_in, const int* in_sizes, int n_in,
                              void* d_out, int out_size, void* d_ws, size_t ws_size,
                              hipStream_t stream) {
  const float* x     = (const float*)d_in[0];
  const float* wq    = (const float*)d_in[1];
  const float* bq    = (const float*)d_in[2];
  const float* wk    = (const float*)d_in[3];
  const float* bk    = (const float*)d_in[4];
  const float* wv    = (const float*)d_in[5];
  const float* bv    = (const float*)d_in[6];
  const float* alpha = (const float*)d_in[7];
  float* out = (float*)d_out;

  char* ws = (char*)d_ws;
  _Float16* w_h  = (_Float16*)(ws);                    // 640*512*2   = 655360
  float*    bias = (float*)(ws + 655360);              // 640*4       = 2560
  float*    Mbuf = (float*)(ws + 657920);              // 4*4096*4    = 65536
  _Float16* xt   = (_Float16*)(ws + 723456);           // 4*4096*512*2= 16777216
  _Float16* q_h  = (_Float16*)(ws + 17500672);         // 4*4096*64*2 = 2097152
  _Float16* k_h  = (_Float16*)(ws + 19597824);         // 4*4096*64*2 = 2097152
  _Float16* v_h  = (_Float16*)(ws + 21694976);         // 4*512*4096*2= 16777216
                                                       // total ~38.5 MB

  prep_w<<<1280, 256, 0, stream>>>(wq, wk, wv, bq, bk, bv, w_h, bias);
  transpose_x<<<dim3(64, 8, BB), 256, 0, stream>>>(x, xt);
  proj_qkv<<<dim3(10, 64, BB), 64, 0, stream>>>(w_h, bias, xt, q_h, k_h, v_h);
  rowmax<<<dim3(64, BB), 256, 0, stream>>>(q_h, k_h, Mbuf);
  attn_pv<<<1024, 256, 0, stream>>>(q_h, k_h, v_h, Mbuf, x, alpha, out);
}

// Round 2
// 326.751 us; speedup vs baseline: 1.2767x; 1.2767x over previous
//
#include <hip/hip_runtime.h>

// Problem constants (fixed by reference: B=4, C=512, H=W=64, MID=64)
#define BB 4
#define CD 512
#define NP 4096
#define MID 64
#define VSTR 88   // LDS row stride in halves: 176B rows, 16B-aligned, ~2-way banks

typedef _Float16 half8 __attribute__((ext_vector_type(8)));
typedef _Float16 half4 __attribute__((ext_vector_type(4)));
typedef float floatx4 __attribute__((ext_vector_type(4)));

#define LOG2E 1.4426950408889634f

// ---------------------------------------------------------------------------
// Kernel 1: pack wq|wk|wv -> fp16 [640][512], concat biases (fp32 [640]).
// log2(e) folded into wq/bq so softmax can use exp2 (raw v_exp_f32).
// ---------------------------------------------------------------------------
__global__ __launch_bounds__(256) void prep_w(
    const float* __restrict__ wq, const float* __restrict__ wk,
    const float* __restrict__ wv, const float* __restrict__ bq,
    const float* __restrict__ bk, const float* __restrict__ bv,
    _Float16* __restrict__ w_h, float* __restrict__ bias) {
  int idx = blockIdx.x * 256 + threadIdx.x;
  for (int i = idx; i < 640 * 512; i += gridDim.x * 256) {
    int r = i >> 9, c = i & 511;
    float v = (r < 64) ? wq[(r << 9) + c] * LOG2E
            : (r < 128) ? wk[((r - 64) << 9) + c]
                        : wv[((r - 128) << 9) + c];
    w_h[i] = (_Float16)v;
  }
  if (idx < 640) {
    float v = (idx < 64) ? bq[idx] * LOG2E
            : (idx < 128) ? bk[idx - 64]
                          : bv[idx - 128];
    bias[idx] = v;
  }
}

// ---------------------------------------------------------------------------
// Kernel 2: transpose x [b][c][n] fp32 -> xt [b][n][c] fp16 (64x64 LDS tiles)
// ---------------------------------------------------------------------------
__global__ __launch_bounds__(256) void transpose_x(const float* __restrict__ x,
                                                   _Float16* __restrict__ xt) {
  __shared__ float tile[64][65];
  int b = blockIdx.z, c0 = blockIdx.y * 64, n0 = blockIdx.x * 64;
  int t = threadIdx.x;
  const float* xb = x + (size_t)b * CD * NP;
#pragma unroll
  for (int k = 0; k < 16; k++) {
    int cl = k * 4 + (t >> 6);
    int nl = t & 63;
    tile[cl][nl] = xb[(size_t)(c0 + cl) * NP + n0 + nl];
  }
  __syncthreads();
  // write phase: each thread packs 8 contiguous c into a half8 (coalesced 16B)
  _Float16* xtb = xt + ((size_t)b * NP + n0) * CD + c0;
#pragma unroll
  for (int k = 0; k < 2; k++) {
    int nl = k * 32 + (t >> 3);
    int cl = (t & 7) * 8;
    half8 pk;
#pragma unroll
    for (int i = 0; i < 8; i++) pk[i] = (_Float16)tile[cl + i][nl];
    *(half8*)(xtb + (size_t)nl * CD + cl) = pk;
  }
}

// ---------------------------------------------------------------------------
// Kernel 3: fused QKV projection. One wave per block, 64 rows x 64 cols tile.
// D[row=w_row][col=n] = sum_c W[row][c] * xt[n][c]  (A=W, B=xt)
// q,k stored [b][n][64] fp16; v stored [b][d][n] fp16 (via LDS bounce for
// coalesced 16B stores).
// ---------------------------------------------------------------------------
__global__ __launch_bounds__(64) void proj_qkv(
    const _Float16* __restrict__ w_h, const float* __restrict__ bias,
    const _Float16* __restrict__ xt, _Float16* __restrict__ q_h,
    _Float16* __restrict__ k_h, _Float16* __restrict__ v_h) {
  __shared__ _Float16 st[64 * 72];
  int lane = threadIdx.x;
  int col = lane & 15, quad = lane >> 4;
  int rb = blockIdx.x;          // 0..9  (64 W-rows each)
  int nb = blockIdx.y;          // 0..63 (64 positions each)
  int b = blockIdx.z;
  int r0 = rb * 64, n0 = nb * 64;
  const _Float16* xtb = xt + ((size_t)b * NP + n0) * CD;

  floatx4 acc[4][4] = {};
  for (int c = 0; c < CD; c += 32) {
    half8 a[4], bf[4];
#pragma unroll
    for (int i = 0; i < 4; i++)
      a[i] = *(const half8*)(w_h + (size_t)(r0 + i * 16 + col) * CD + c + quad * 8);
#pragma unroll
    for (int j = 0; j < 4; j++)
      bf[j] = *(const half8*)(xtb + (size_t)(j * 16 + col) * CD + c + quad * 8);
#pragma unroll
    for (int i = 0; i < 4; i++)
#pragma unroll
      for (int j = 0; j < 4; j++)
        acc[i][j] = __builtin_amdgcn_mfma_f32_16x16x32_f16(a[i], bf[j], acc[i][j], 0, 0, 0);
  }

  if (rb < 2) {
#pragma unroll
    for (int i = 0; i < 4; i++) {
      float bi[4];
#pragma unroll
      for (int rr = 0; rr < 4; rr++) bi[rr] = bias[r0 + i * 16 + quad * 4 + rr];
      _Float16* dst = (rb == 0 ? q_h : k_h) + (size_t)b * NP * MID;
#pragma unroll
      for (int j = 0; j < 4; j++) {
        int n = n0 + j * 16 + col;
        half4 pk;
#pragma unroll
        for (int rr = 0; rr < 4; rr++) pk[rr] = (_Float16)(acc[i][j][rr] + bi[rr]);
        *(half4*)(dst + (size_t)n * MID + i * 16 + quad * 4) = pk;
      }
    }
  } else {
    // V tile: bounce through LDS so global stores are row-contiguous b128
#pragma unroll
    for (int i = 0; i < 4; i++) {
      float bi[4];
#pragma unroll
      for (int rr = 0; rr < 4; rr++) bi[rr] = bias[r0 + i * 16 + quad * 4 + rr];
#pragma unroll
      for (int j = 0; j < 4; j++)
#pragma unroll
        for (int rr = 0; rr < 4; rr++)
          st[(i * 16 + quad * 4 + rr) * 72 + j * 16 + col] =
              (_Float16)(acc[i][j][rr] + bi[rr]);
    }
    int dbase = (rb - 2) * 64;
    // single wave: compiler inserts lgkmcnt wait between ds_write and ds_read
#pragma unroll
    for (int k = 0; k < 8; k++) {
      int u = lane + k * 64;
      int row = u >> 3, off = (u & 7) * 8;
      *(half8*)(v_h + ((size_t)b * CD + dbase + row) * NP + n0 + off) =
          *(const half8*)(st + row * 72 + off);
    }
  }
}

// ---------------------------------------------------------------------------
// Kernel 4: row max of S (log2-domain). Each block: 16 queries; 4 waves split
// the 4096 keys into 1024-key slices; LDS max-reduce. Grid (256, B).
// ---------------------------------------------------------------------------
__global__ __launch_bounds__(256) void rowmax(const _Float16* __restrict__ q_h,
                                              const _Float16* __restrict__ k_h,
                                              float* __restrict__ M) {
  int qb16 = blockIdx.x, b = blockIdx.y;
  int t = threadIdx.x, w = t >> 6, lane = t & 63;
  int col = lane & 15, quad = lane >> 4;
  int q0 = qb16 * 16;
  const _Float16* qp = q_h + ((size_t)b * NP + q0) * MID;
  half8 bq0 = *(const half8*)(qp + (size_t)col * MID + quad * 8);
  half8 bq1 = *(const half8*)(qp + (size_t)col * MID + 32 + quad * 8);
  const _Float16* kp = k_h + (size_t)b * NP * MID + (size_t)w * 1024 * MID;
  float m = -1e30f;
#pragma unroll 4
  for (int n = 0; n < 1024; n += 16) {
    half8 ak0 = *(const half8*)(kp + (size_t)(n + col) * MID + quad * 8);
    half8 ak1 = *(const half8*)(kp + (size_t)(n + col) * MID + 32 + quad * 8);
    floatx4 s = {};
    s = __builtin_amdgcn_mfma_f32_16x16x32_f16(ak0, bq0, s, 0, 0, 0);
    s = __builtin_amdgcn_mfma_f32_16x16x32_f16(ak1, bq1, s, 0, 0, 0);
    m = fmaxf(m, fmaxf(fmaxf(s[0], s[1]), fmaxf(s[2], s[3])));
  }
  // lane holds max over its keys for q = q0+col; reduce across quads
  m = fmaxf(m, __shfl_xor(m, 16));
  m = fmaxf(m, __shfl_xor(m, 32));
  __shared__ float red[4][16];
  if (quad == 0) red[w][col] = m;
  __syncthreads();
  if (t < 16) {
    float mm = fmaxf(fmaxf(red[0][t], red[1][t]), fmaxf(red[2][t], red[3][t]));
    M[(size_t)b * NP + q0 + t] = mm;
  }
}

// ---------------------------------------------------------------------------
// Kernel 5: attention + PV + epilogue, v2.
// Block = 4 waves = 64 queries x 256 d. Wave w: scores for q-tile w (16 q,
// transposed MFMA A=K,B=Q -> packed half4 pbuf writes), PV for 64q x 64d
// (d-range w*64). 3 barriers/chunk. Grid 512, XCD-swizzled: each XCD gets
// one (batch, d-half) -> V-slice 2MB + K 0.5MB resident in 4MB L2.
// ---------------------------------------------------------------------------
__global__ __launch_bounds__(256, 2) void attn_pv(
    const _Float16* __restrict__ q_h, const _Float16* __restrict__ k_h,
    const _Float16* __restrict__ v_h, const float* __restrict__ M,
    const float* __restrict__ x, const float* __restrict__ alpha_p,
    float* __restrict__ out) {
  int bid = blockIdx.x;
  int xcd = bid & 7, idx = bid >> 3;
  int b = xcd >> 1, ds = xcd & 1, qb = idx;   // b 0..3, ds 0..1, qb 0..63

  int t = threadIdx.x, w = t >> 6, lane = t & 63;
  int col = lane & 15, quad = lane >> 4;
  int q0 = qb * 64;
  int qw = q0 + w * 16;           // this wave's score q-tile
  int d0 = ds * 256 + w * 64;     // this wave's PV d-range (global d)

  __shared__ _Float16 vtile[256 * VSTR];
  __shared__ _Float16 ktile[64 * VSTR];
  __shared__ _Float16 pbuf[64 * VSTR];
  __shared__ float lbuf[64];

  const _Float16* qp = q_h + ((size_t)b * NP + qw) * MID;
  half8 bq0 = *(const half8*)(qp + (size_t)col * MID + quad * 8);
  half8 bq1 = *(const half8*)(qp + (size_t)col * MID + 32 + quad * 8);
  float Mq = M[(size_t)b * NP + qw + col];

  const _Float16* kp = k_h + (size_t)b * NP * MID;
  const _Float16* vp = v_h + ((size_t)b * CD + ds * 256) * NP;

  floatx4 acc[4][4] = {};   // [dt][qt]
  float lp = 0.f;

  for (int nc = 0; nc < NP; nc += 64) {
    __syncthreads();
    // stage V 256x64 halves (32KB) + K 64x64 (8KB), coalesced 16B units
#pragma unroll
    for (int k2 = 0; k2 < 8; k2++) {
      int u = t + k2 * 256;
      int dd = u >> 3, off = (u & 7) * 8;
      *(half8*)(vtile + dd * VSTR + off) =
          *(const half8*)(vp + (size_t)dd * NP + nc + off);
    }
#pragma unroll
    for (int k2 = 0; k2 < 2; k2++) {
      int u = t + k2 * 256;
      int nn = u >> 3, off = (u & 7) * 8;
      *(half8*)(ktile + nn * VSTR + off) =
          *(const half8*)(kp + (size_t)(nc + nn) * MID + off);
    }
    __syncthreads();

    // scores transposed: D[key=kt*16+quad*4+r][q=qw+col]; packed pbuf write
#pragma unroll
    for (int kt = 0; kt < 4; kt++) {
      half8 ak0 = *(const half8*)(ktile + (kt * 16 + col) * VSTR + quad * 8);
      half8 ak1 = *(const half8*)(ktile + (kt * 16 + col) * VSTR + 32 + quad * 8);
      floatx4 s = {};
      s = __builtin_amdgcn_mfma_f32_16x16x32_f16(ak0, bq0, s, 0, 0, 0);
      s = __builtin_amdgcn_mfma_f32_16x16x32_f16(ak1, bq1, s, 0, 0, 0);
      half4 pk;
#pragma unroll
      for (int r = 0; r < 4; r++) {
        float p = exp2f(s[r] - Mq);
        lp += p;
        pk[r] = (_Float16)p;
      }
      *(half4*)(pbuf + (w * 16 + col) * VSTR + kt * 16 + quad * 4) = pk;
    }
    __syncthreads();

    // PV: O^T tile, A=V[d][n], B=P^T[n][q]; av reused across 4 q-tiles
#pragma unroll
    for (int f = 0; f < 2; f++) {
      half8 bp[4];
#pragma unroll
      for (int qt = 0; qt < 4; qt++)
        bp[qt] = *(const half8*)(pbuf + (qt * 16 + col) * VSTR + f * 32 + quad * 8);
#pragma unroll
      for (int dt = 0; dt < 4; dt++) {
        half8 av = *(const half8*)(vtile + (w * 64 + dt * 16 + col) * VSTR + f * 32 + quad * 8);
#pragma unroll
        for (int qt = 0; qt < 4; qt++)
          acc[dt][qt] = __builtin_amdgcn_mfma_f32_16x16x32_f16(av, bp[qt], acc[dt][qt], 0, 0, 0);
      }
    }
  }

  // l: lane's partial is for q = qw+col; reduce across quads only
  lp += __shfl_xor(lp, 16);
  lp += __shfl_xor(lp, 32);
  if (quad == 0) lbuf[w * 16 + col] = lp;
  __syncthreads();

  float alpha = alpha_p[0];
  const float* xp = x + ((size_t)b * CD + d0) * NP;
  float* op = out + ((size_t)b * CD + d0) * NP;
#pragma unroll
  for (int qt = 0; qt < 4; qt++) {
    float linv = alpha / lbuf[qt * 16 + col];
#pragma unroll
    for (int dt = 0; dt < 4; dt++) {
#pragma unroll
      for (int r = 0; r < 4; r++) {
        size_t o = (size_t)(dt * 16 + quad * 4 + r) * NP + q0 + qt * 16 + col;
        op[o] = acc[dt][qt][r] * linv + xp[o];
      }
    }
  }
}

// ---------------------------------------------------------------------------
extern "C" void kernel_launch(void* const* d_in, const int* in_sizes, int n_in,
                              void* d_out, int out_size, void* d_ws, size_t ws_size,
                              hipStream_t stream) {
  const float* x     = (const float*)d_in[0];
  const float* wq    = (const float*)d_in[1];
  const float* bq    = (const float*)d_in[2];
  const float* wk    = (const float*)d_in[3];
  const float* bk    = (const float*)d_in[4];
  const float* wv    = (const float*)d_in[5];
  const float* bv    = (const float*)d_in[6];
  const float* alpha = (const float*)d_in[7];
  float* out = (float*)d_out;

  char* ws = (char*)d_ws;
  _Float16* w_h  = (_Float16*)(ws);                    // 640*512*2   = 655360
  float*    bias = (float*)(ws + 655360);              // 640*4       = 2560
  float*    Mbuf = (float*)(ws + 657920);              // 4*4096*4    = 65536
  _Float16* xt   = (_Float16*)(ws + 723456);           // 4*4096*512*2= 16777216
  _Float16* q_h  = (_Float16*)(ws + 17500672);         // 4*4096*64*2 = 2097152
  _Float16* k_h  = (_Float16*)(ws + 19597824);         // 4*4096*64*2 = 2097152
  _Float16* v_h  = (_Float16*)(ws + 21694976);         // 4*512*4096*2= 16777216

  prep_w<<<1280, 256, 0, stream>>>(wq, wk, wv, bq, bk, bv, w_h, bias);
  transpose_x<<<dim3(64, 8, BB), 256, 0, stream>>>(x, xt);
  proj_qkv<<<dim3(10, 64, BB), 64, 0, stream>>>(w_h, bias, xt, q_h, k_h, v_h);
  rowmax<<<dim3(256, BB), 256, 0, stream>>>(q_h, k_h, Mbuf);
  attn_pv<<<512, 256, 0, stream>>>(q_h, k_h, v_h, Mbuf, x, alpha, out);
}